// Round 5
// baseline (415.354 us; speedup 1.0000x reference)
//
#include <hip/hip_runtime.h>
#include <cstdint>
#include <cstddef>

typedef __attribute__((ext_vector_type(8))) __bf16 bf16x8;
typedef __attribute__((ext_vector_type(4))) __bf16 bf16x4;
typedef __attribute__((ext_vector_type(4))) float f32x4;

#define DEVI __device__ __forceinline__

DEVI void gload_lds16(const void* g, void* l) {
    __builtin_amdgcn_global_load_lds((const __attribute__((address_space(1))) void*)g,
                                     (__attribute__((address_space(3))) void*)l, 16, 0, 0);
}

// ---------------- f32 -> bf16 conversion of x and all weights ----------------
__global__ __launch_bounds__(256) void cvt_all(
    const float* __restrict__ x, const float* __restrict__ wq,
    const float* __restrict__ wk, const float* __restrict__ wv,
    const float* __restrict__ wo,
    bf16x4* __restrict__ xb, bf16x4* __restrict__ wqb, bf16x4* __restrict__ wkb,
    bf16x4* __restrict__ wvb, bf16x4* __restrict__ wob)
{
    int i = blockIdx.x * 256 + threadIdx.x;
    const int stride = gridDim.x * 256;
    for (; i < 1835008; i += stride) {
        const float4* s; bf16x4* d; int j;
        if (i < 1048576)      { s = (const float4*)x;  d = xb;  j = i; }
        else if (i < 1310720) { s = (const float4*)wq; d = wqb; j = i - 1048576; }
        else if (i < 1441792) { s = (const float4*)wk; d = wkb; j = i - 1310720; }
        else if (i < 1572864) { s = (const float4*)wv; d = wvb; j = i - 1441792; }
        else                  { s = (const float4*)wo; d = wob; j = i - 1572864; }
        float4 v = s[j];
        bf16x4 o = { (__bf16)v.x, (__bf16)v.y, (__bf16)v.z, (__bf16)v.w };
        d[j] = o;
    }
}

// ---------------- RoPE tables: sin/cos[t][pair], T=2048, 32 pairs ----------------
__global__ __launch_bounds__(256) void rope_tables(float* __restrict__ sint, float* __restrict__ cost)
{
    int i = blockIdx.x * 256 + threadIdx.x;   // 0..65535
    int t = i >> 5, p = i & 31;
    float inv = powf(10000.0f, -(float)p / 32.0f);
    float f = (float)t * inv;
    float s, c;
    sincosf(f, &s, &c);
    sint[i] = s;
    cost[i] = c;
}

// ---------------- QKV projection GEMM (128x128 tile, BK=64, bf16 MFMA) ----------------
__global__ __launch_bounds__(256) void qkv_gemm(
    const __bf16* __restrict__ xb, const __bf16* __restrict__ wqb,
    const __bf16* __restrict__ wkb, const __bf16* __restrict__ wvb,
    const float* __restrict__ sint, const float* __restrict__ cost,
    __bf16* __restrict__ Qo, __bf16* __restrict__ Ko, __bf16* __restrict__ Vo)
{
    __shared__ __bf16 As[8192];   // [128 rows][64 cols], 128B rows, chunk-swizzled
    __shared__ __bf16 Bs[8192];
    const int tid = threadIdx.x;
    const int lane = tid & 63;
    const int wid = tid >> 6;
    const int wm = (wid >> 1) * 64, wn = (wid & 1) * 64;
    const int m0 = blockIdx.y * 128;
    const int n0 = blockIdx.x * 128;

    const __bf16* bsrc;
    if (n0 < 1024)      bsrc = wqb + (size_t)n0 * 1024;
    else if (n0 < 1536) bsrc = wkb + (size_t)(n0 - 1024) * 1024;
    else                bsrc = wvb + (size_t)(n0 - 1536) * 1024;
    const __bf16* asrc = xb + (size_t)m0 * 1024;

    f32x4 acc[4][4] = {};
    const int srow = tid >> 3, schunk = tid & 7;

    for (int k0 = 0; k0 < 1024; k0 += 64) {
        __syncthreads();
#pragma unroll
        for (int it = 0; it < 4; ++it) {
            int r = srow + it * 32;
            int gc = (schunk ^ (r & 7)) * 8;      // pre-swizzled global source chunk
            gload_lds16(asrc + (size_t)r * 1024 + k0 + gc, (char*)As + r * 128 + schunk * 16);
            gload_lds16(bsrc + (size_t)r * 1024 + k0 + gc, (char*)Bs + r * 128 + schunk * 16);
        }
        __syncthreads();
#pragma unroll
        for (int ks = 0; ks < 2; ++ks) {
            bf16x8 af[4], bfv[4];
#pragma unroll
            for (int i = 0; i < 4; ++i) {
                int ra = wm + i * 16 + (lane & 15);
                af[i] = *(const bf16x8*)((const char*)As + ra * 128 + (((ks * 4 + (lane >> 4)) ^ (ra & 7)) * 16));
                int rb = wn + i * 16 + (lane & 15);
                bfv[i] = *(const bf16x8*)((const char*)Bs + rb * 128 + (((ks * 4 + (lane >> 4)) ^ (rb & 7)) * 16));
            }
#pragma unroll
            for (int mi = 0; mi < 4; ++mi)
#pragma unroll
                for (int ni = 0; ni < 4; ++ni)
                    acc[mi][ni] = __builtin_amdgcn_mfma_f32_16x16x32_bf16(af[mi], bfv[ni], acc[mi][ni], 0, 0, 0);
        }
    }

    const int rg = lane >> 4, cf = lane & 15;
#pragma unroll
    for (int mi = 0; mi < 4; ++mi) {
#pragma unroll
        for (int ni = 0; ni < 4; ++ni) {
#pragma unroll
            for (int r = 0; r < 4; ++r) {
                float v = acc[mi][ni][r];
                float pv = __shfl_xor(v, 1, 64);    // partner column d^1 (same rows)
                int m = m0 + wm + mi * 16 + rg * 4 + r;
                int n = n0 + wn + ni * 16 + cf;
                int b = m >> 11;
                int t = m & 2047;
                if (n < 1024) {
                    int h = n >> 6, d = n & 63;
                    float s = sint[t * 32 + (d >> 1)], c = cost[t * 32 + (d >> 1)];
                    float o = (d & 1) ? (pv * s + v * c) : (v * c - pv * s);
                    Qo[((size_t)(b * 16 + h) * 2048 + t) * 64 + d] = (__bf16)(o * 0.125f);
                } else if (n < 1536) {
                    int nn = n - 1024;
                    int h = nn >> 6, d = nn & 63;
                    float s = sint[t * 32 + (d >> 1)], c = cost[t * 32 + (d >> 1)];
                    float o = (d & 1) ? (pv * s + v * c) : (v * c - pv * s);
                    Ko[((size_t)(b * 8 + h) * 2048 + t) * 64 + d] = (__bf16)o;
                } else {
                    int nn = n - 1536;
                    int h = nn >> 6, d = nn & 63;
                    Vo[((size_t)(b * 8 + h) * 2048 + t) * 64 + d] = (__bf16)v;
                }
            }
        }
    }
}

// ---------------- V transpose: V[bh][t][d] -> VT[bh][d][t] ----------------
__global__ __launch_bounds__(256) void v_transpose(const __bf16* __restrict__ Vg, __bf16* __restrict__ VTg)
{
    __shared__ __bf16 tile[64][72];
    const int tid = threadIdx.x;
    const int t0 = blockIdx.x * 64;
    const int bh = blockIdx.y;
    const size_t base = (size_t)bh * 2048 * 64;
    const int rr = tid >> 3, c8 = (tid & 7) * 8;
#pragma unroll
    for (int it = 0; it < 2; ++it) {
        int tt = rr + it * 32;
        *(bf16x8*)(&tile[tt][c8]) = *(const bf16x8*)(Vg + base + (size_t)(t0 + tt) * 64 + c8);
    }
    __syncthreads();
#pragma unroll
    for (int it = 0; it < 2; ++it) {
        int d = rr + it * 32;
        bf16x8 o;
#pragma unroll
        for (int j = 0; j < 8; ++j) o[j] = tile[c8 + j][d];
        *(bf16x8*)(VTg + base + (size_t)d * 2048 + t0 + c8) = o;
    }
}

// ---------------- Flash attention pass 1: split-KV partials ----------------
// Unit u: bh = u>>7, rem = u&127, j = 63-(rem>>1) (32-row q-tile), s = rem&1 (KV half).
// ntk = j/2+1 64-KV tiles; unit handles tiles [s*ntk/2, (s+1)*ntk/2).
// Diagonal tile is ALWAYS nt==ntk-1 (falls in whichever unit's range contains it);
// mask condition needs rowoff = (j&1)*32 (odd j = upper 32 rows of the 64-block).
__global__ __launch_bounds__(64, 4) void attn_part(
    const __bf16* __restrict__ Qg, const __bf16* __restrict__ Kg,
    const __bf16* __restrict__ VTg,
    __bf16* __restrict__ Op0, __bf16* __restrict__ Op1, float* __restrict__ mlp)
{
    __shared__ char Pl[4096];     // 32 rows x 64 cols bf16, swizzled
    const int lane = threadIdx.x & 63;
    const int u = blockIdx.x;
    const int bhu = u >> 7;
    const int rem = u & 127;
    const int j = 63 - (rem >> 1);
    const int s = rem & 1;
    const int b = bhu >> 4, h = bhu & 15, kvh = h >> 1;
    const int ntk = (j >> 1) + 1;
    const int lo = (s * ntk) >> 1;
    const int hi = ((s + 1) * ntk) >> 1;
    const int maskt = ntk - 1;                 // diagonal tile (R4 bug: skipped for odd j)
    const int rowoff = (j & 1) * 32;           // odd j sits in the upper half of the 64-row block
    const int r0 = j * 32;
    const size_t qbase = (size_t)(b * 16 + h) * 2048 * 64;
    const size_t kbase = (size_t)(b * 8 + kvh) * 2048 * 64;
    const int rg = lane >> 4, cf = lane & 15;

    // Q fragments in registers (already scaled by 0.125)
    bf16x8 qf[2][2];
#pragma unroll
    for (int mi = 0; mi < 2; ++mi)
#pragma unroll
        for (int ks = 0; ks < 2; ++ks)
            qf[mi][ks] = *(const bf16x8*)(Qg + qbase + (size_t)(r0 + mi * 16 + cf) * 64 + ks * 32 + rg * 8);

    f32x4 oacc[2][4] = {};
    float mst[2][4], lst[2][4];
#pragma unroll
    for (int i = 0; i < 2; ++i)
#pragma unroll
        for (int r = 0; r < 4; ++r) { mst[i][r] = -3.0e38f; lst[i][r] = 0.0f; }

    for (int nt = lo; nt < hi; ++nt) {
        const int n0 = nt * 64;
        // K fragments direct from global (L2-resident)
        bf16x8 kf[2][4];
#pragma unroll
        for (int ks = 0; ks < 2; ++ks)
#pragma unroll
            for (int ni = 0; ni < 4; ++ni)
                kf[ks][ni] = *(const bf16x8*)(Kg + kbase + (size_t)(n0 + ni * 16 + cf) * 64 + ks * 32 + rg * 8);

        // S = Q K^T
        f32x4 sacc[2][4] = {};
        __builtin_amdgcn_s_setprio(1);
#pragma unroll
        for (int ks = 0; ks < 2; ++ks)
#pragma unroll
            for (int mi = 0; mi < 2; ++mi)
#pragma unroll
                for (int ni = 0; ni < 4; ++ni)
                    sacc[mi][ni] = __builtin_amdgcn_mfma_f32_16x16x32_bf16(qf[mi][ks], kf[ks][ni], sacc[mi][ni], 0, 0, 0);
        __builtin_amdgcn_s_setprio(0);

        // V fragments for this tile (issued early, consumed after softmax)
        bf16x8 vf[2][4];
#pragma unroll
        for (int ks = 0; ks < 2; ++ks)
#pragma unroll
            for (int df = 0; df < 4; ++df)
                vf[ks][df] = *(const bf16x8*)(VTg + kbase + (size_t)(df * 16 + cf) * 2048 + n0 + ks * 32 + rg * 8);

        // causal mask on the diagonal tile
        if (nt == maskt) {
#pragma unroll
            for (int mi = 0; mi < 2; ++mi)
#pragma unroll
                for (int ni = 0; ni < 4; ++ni)
#pragma unroll
                    for (int r = 0; r < 4; ++r)
                        if (ni * 16 + cf > rowoff + mi * 16 + rg * 4 + r)
                            sacc[mi][ni][r] = -3.0e38f;
        }

        // online softmax (rows independent -> ILP)
#pragma unroll
        for (int mi = 0; mi < 2; ++mi) {
#pragma unroll
            for (int r = 0; r < 4; ++r) {
                float rmax = fmaxf(fmaxf(sacc[mi][0][r], sacc[mi][1][r]),
                                   fmaxf(sacc[mi][2][r], sacc[mi][3][r]));
#pragma unroll
                for (int off = 1; off < 16; off <<= 1)
                    rmax = fmaxf(rmax, __shfl_xor(rmax, off, 64));
                float mold = mst[mi][r];
                float mnew = fmaxf(mold, rmax);
                float sf = __expf(mold - mnew);
                float rs = 0.0f;
#pragma unroll
                for (int ni = 0; ni < 4; ++ni) {
                    float p = __expf(sacc[mi][ni][r] - mnew);
                    sacc[mi][ni][r] = p;
                    rs += p;
                }
#pragma unroll
                for (int off = 1; off < 16; off <<= 1)
                    rs += __shfl_xor(rs, off, 64);
                mst[mi][r] = mnew;
                lst[mi][r] = lst[mi][r] * sf + rs;
#pragma unroll
                for (int df = 0; df < 4; ++df) oacc[mi][df][r] *= sf;   // per-ROW rescale
            }
        }

        // P -> wave-local LDS (bf16, swizzled)
#pragma unroll
        for (int mi = 0; mi < 2; ++mi)
#pragma unroll
            for (int ni = 0; ni < 4; ++ni)
#pragma unroll
                for (int r = 0; r < 4; ++r) {
                    int pr = mi * 16 + rg * 4 + r;
                    int pc = ni * 16 + cf;
                    *(__bf16*)(Pl + pr * 128 + (((pc >> 3) ^ (pr & 7)) * 8 + (pc & 7)) * 2) =
                        (__bf16)sacc[mi][ni][r];
                }

        // O += P V
        __builtin_amdgcn_s_setprio(1);
#pragma unroll
        for (int ks = 0; ks < 2; ++ks) {
            bf16x8 pf[2];
#pragma unroll
            for (int mi = 0; mi < 2; ++mi) {
                int pr = mi * 16 + cf;
                pf[mi] = *(const bf16x8*)(Pl + pr * 128 + (((ks * 4 + rg) ^ (pr & 7)) * 16));
            }
#pragma unroll
            for (int mi = 0; mi < 2; ++mi)
#pragma unroll
                for (int df = 0; df < 4; ++df)
                    oacc[mi][df] = __builtin_amdgcn_mfma_f32_16x16x32_bf16(pf[mi], vf[ks][df], oacc[mi][df], 0, 0, 0);
        }
        __builtin_amdgcn_s_setprio(0);
    }

    // write partials (unnormalized O, m, l)
    __bf16* Op = (u < 3072) ? (Op0 + (size_t)u * 2048) : (Op1 + (size_t)(u - 3072) * 2048);
#pragma unroll
    for (int mi = 0; mi < 2; ++mi)
#pragma unroll
        for (int df = 0; df < 4; ++df)
#pragma unroll
            for (int r = 0; r < 4; ++r)
                Op[(mi * 16 + rg * 4 + r) * 64 + df * 16 + cf] = (__bf16)oacc[mi][df][r];
    if (cf == 0) {
#pragma unroll
        for (int mi = 0; mi < 2; ++mi)
#pragma unroll
            for (int r = 0; r < 4; ++r) {
                int row = mi * 16 + rg * 4 + r;
                mlp[u * 64 + row * 2]     = mst[mi][r];
                mlp[u * 64 + row * 2 + 1] = lst[mi][r];
            }
    }
}

// ---------------- Flash attention pass 2: combine the 2 splits ----------------
__global__ __launch_bounds__(64) void attn_combine(
    const __bf16* __restrict__ Op0, const __bf16* __restrict__ Op1,
    const float* __restrict__ mlp, __bf16* __restrict__ Yg)
{
    const int c = blockIdx.x;          // 0..2047
    const int bh = c >> 6, j = c & 63;
    const int b = bh >> 4, h = bh & 15;
    const int lane = threadIdx.x & 63;
    const int row = lane & 31, d0 = (lane >> 5) * 32;
    const int u0 = (bh << 7) + (63 - j) * 2, u1 = u0 + 1;
    const __bf16* P0 = ((u0 < 3072) ? (Op0 + (size_t)u0 * 2048) : (Op1 + (size_t)(u0 - 3072) * 2048)) + row * 64 + d0;
    const __bf16* P1 = ((u1 < 3072) ? (Op0 + (size_t)u1 * 2048) : (Op1 + (size_t)(u1 - 3072) * 2048)) + row * 64 + d0;
    float m0 = mlp[u0 * 64 + row * 2], l0 = mlp[u0 * 64 + row * 2 + 1];
    float m1 = mlp[u1 * 64 + row * 2], l1 = mlp[u1 * 64 + row * 2 + 1];
    float M = fmaxf(m0, m1);
    float w0 = __expf(m0 - M), w1 = __expf(m1 - M);
    float inv = 1.0f / (l0 * w0 + l1 * w1);
    int t = j * 32 + row;
    __bf16* yp = Yg + ((size_t)b * 2048 + t) * 1024 + h * 64 + d0;
#pragma unroll
    for (int cb = 0; cb < 4; ++cb) {
        bf16x8 a = *(const bf16x8*)(P0 + cb * 8);
        bf16x8 v = *(const bf16x8*)(P1 + cb * 8);
        bf16x8 o;
#pragma unroll
        for (int e = 0; e < 8; ++e)
            o[e] = (__bf16)(((float)a[e] * w0 + (float)v[e] * w1) * inv);
        *(bf16x8*)(yp + cb * 8) = o;
    }
}

// ---------------- Output projection GEMM: out = Y @ Wo^T (f32 out) ----------------
__global__ __launch_bounds__(256) void out_gemm(
    const __bf16* __restrict__ Yb, const __bf16* __restrict__ Wob, float* __restrict__ outp)
{
    __shared__ __bf16 As[8192];
    __shared__ __bf16 Bs[8192];
    const int tid = threadIdx.x;
    const int lane = tid & 63;
    const int wid = tid >> 6;
    const int wm = (wid >> 1) * 64, wn = (wid & 1) * 64;
    const int m0 = blockIdx.y * 128;
    const int n0 = blockIdx.x * 128;
    const __bf16* asrc = Yb + (size_t)m0 * 1024;
    const __bf16* bsrc = Wob + (size_t)n0 * 1024;

    f32x4 acc[4][4] = {};
    const int srow = tid >> 3, schunk = tid & 7;

    for (int k0 = 0; k0 < 1024; k0 += 64) {
        __syncthreads();
#pragma unroll
        for (int it = 0; it < 4; ++it) {
            int r = srow + it * 32;
            int gc = (schunk ^ (r & 7)) * 8;
            gload_lds16(asrc + (size_t)r * 1024 + k0 + gc, (char*)As + r * 128 + schunk * 16);
            gload_lds16(bsrc + (size_t)r * 1024 + k0 + gc, (char*)Bs + r * 128 + schunk * 16);
        }
        __syncthreads();
#pragma unroll
        for (int ks = 0; ks < 2; ++ks) {
            bf16x8 af[4], bfv[4];
#pragma unroll
            for (int i = 0; i < 4; ++i) {
                int ra = wm + i * 16 + (lane & 15);
                af[i] = *(const bf16x8*)((const char*)As + ra * 128 + (((ks * 4 + (lane >> 4)) ^ (ra & 7)) * 16));
                int rb = wn + i * 16 + (lane & 15);
                bfv[i] = *(const bf16x8*)((const char*)Bs + rb * 128 + (((ks * 4 + (lane >> 4)) ^ (rb & 7)) * 16));
            }
#pragma unroll
            for (int mi = 0; mi < 4; ++mi)
#pragma unroll
                for (int ni = 0; ni < 4; ++ni)
                    acc[mi][ni] = __builtin_amdgcn_mfma_f32_16x16x32_bf16(af[mi], bfv[ni], acc[mi][ni], 0, 0, 0);
        }
    }

    const int rg = lane >> 4, cf = lane & 15;
#pragma unroll
    for (int mi = 0; mi < 4; ++mi)
#pragma unroll
        for (int ni = 0; ni < 4; ++ni)
#pragma unroll
            for (int r = 0; r < 4; ++r) {
                int m = m0 + wm + mi * 16 + rg * 4 + r;
                int n = n0 + wn + ni * 16 + cf;
                outp[(size_t)m * 1024 + n] = acc[mi][ni][r];
            }
}

// ---------------- launch ----------------
extern "C" void kernel_launch(void* const* d_in, const int* in_sizes, int n_in,
                              void* d_out, int out_size, void* d_ws, size_t ws_size,
                              hipStream_t stream)
{
    const float* x  = (const float*)d_in[0];
    const float* wq = (const float*)d_in[1];
    const float* wk = (const float*)d_in[2];
    const float* wv = (const float*)d_in[3];
    const float* wo = (const float*)d_in[4];

    char* ws = (char*)d_ws;
    __bf16* xb  = (__bf16*)(ws + 0);          // 8,388,608 B
    __bf16* wqb = (__bf16*)(ws + 8388608);    // 2,097,152
    __bf16* wkb = (__bf16*)(ws + 10485760);   // 1,048,576
    __bf16* wvb = (__bf16*)(ws + 11534336);   // 1,048,576
    __bf16* wob = (__bf16*)(ws + 12582912);   // 2,097,152
    __bf16* Qb  = (__bf16*)(ws + 14680064);   // 8,388,608
    __bf16* Kb  = (__bf16*)(ws + 23068672);   // 4,194,304
    __bf16* Vb  = (__bf16*)(ws + 27262976);   // 4,194,304
    __bf16* VTb = (__bf16*)(ws + 31457280);   // 4,194,304
    __bf16* Yb  = (__bf16*)(ws + 35651584);   // 8,388,608
    float* sint = (float*)(ws + 44040192);    // 262,144
    float* cost = (float*)(ws + 44302336);    // 262,144
    // attn split-KV partials: Op0 overlays xb..wvb (dead after qkv_gemm), 3072 units
    __bf16* Op0 = (__bf16*)(ws + 0);          // 3072 * 4096 B = 12,582,912 (== xb+wqb+wkb+wvb)
    __bf16* Op1 = (__bf16*)(ws + 44564480);   // 1024 * 4096 B = 4,194,304
    float*  mlp = (float*)(ws + 48758784);    // 4096 * 256 B  = 1,048,576
    if (ws_size < 49807360) return;           // would fail loudly via absmax

    cvt_all<<<2048, 256, 0, stream>>>(x, wq, wk, wv, wo,
                                      (bf16x4*)xb, (bf16x4*)wqb, (bf16x4*)wkb,
                                      (bf16x4*)wvb, (bf16x4*)wob);
    rope_tables<<<256, 256, 0, stream>>>(sint, cost);
    qkv_gemm<<<dim3(16, 32), 256, 0, stream>>>(xb, wqb, wkb, wvb, sint, cost, Qb, Kb, Vb);
    v_transpose<<<dim3(32, 16), 256, 0, stream>>>(Vb, VTb);
    attn_part<<<4096, 64, 0, stream>>>(Qb, Kb, VTb, Op0, Op1, mlp);
    attn_combine<<<2048, 64, 0, stream>>>(Op0, Op1, mlp, Yb);
    out_gemm<<<dim3(8, 32), 256, 0, stream>>>(Yb, wob, (float*)d_out);
}

// Round 6
// 357.363 us; speedup vs baseline: 1.1623x; 1.1623x over previous
//
#include <hip/hip_runtime.h>
#include <cstdint>
#include <cstddef>

typedef __attribute__((ext_vector_type(8))) __bf16 bf16x8;
typedef __attribute__((ext_vector_type(4))) __bf16 bf16x4;
typedef __attribute__((ext_vector_type(4))) float f32x4;

#define DEVI __device__ __forceinline__

DEVI void gload_lds16(const void* g, void* l) {
    __builtin_amdgcn_global_load_lds((const __attribute__((address_space(1))) void*)g,
                                     (__attribute__((address_space(3))) void*)l, 16, 0, 0);
}

// ---------------- f32 -> bf16 conversion of x and all weights ----------------
__global__ __launch_bounds__(256) void cvt_all(
    const float* __restrict__ x, const float* __restrict__ wq,
    const float* __restrict__ wk, const float* __restrict__ wv,
    const float* __restrict__ wo,
    bf16x4* __restrict__ xb, bf16x4* __restrict__ wqb, bf16x4* __restrict__ wkb,
    bf16x4* __restrict__ wvb, bf16x4* __restrict__ wob)
{
    int i = blockIdx.x * 256 + threadIdx.x;
    const int stride = gridDim.x * 256;
    for (; i < 1835008; i += stride) {
        const float4* s; bf16x4* d; int j;
        if (i < 1048576)      { s = (const float4*)x;  d = xb;  j = i; }
        else if (i < 1310720) { s = (const float4*)wq; d = wqb; j = i - 1048576; }
        else if (i < 1441792) { s = (const float4*)wk; d = wkb; j = i - 1310720; }
        else if (i < 1572864) { s = (const float4*)wv; d = wvb; j = i - 1441792; }
        else                  { s = (const float4*)wo; d = wob; j = i - 1572864; }
        float4 v = s[j];
        bf16x4 o = { (__bf16)v.x, (__bf16)v.y, (__bf16)v.z, (__bf16)v.w };
        d[j] = o;
    }
}

// ---------------- RoPE tables: sin/cos[t][pair], T=2048, 32 pairs ----------------
__global__ __launch_bounds__(256) void rope_tables(float* __restrict__ sint, float* __restrict__ cost)
{
    int i = blockIdx.x * 256 + threadIdx.x;   // 0..65535
    int t = i >> 5, p = i & 31;
    float inv = powf(10000.0f, -(float)p / 32.0f);
    float f = (float)t * inv;
    float s, c;
    sincosf(f, &s, &c);
    sint[i] = s;
    cost[i] = c;
}

// ---------------- QKV projection GEMM (128x128 tile, BK=64, bf16 MFMA) ----------------
__global__ __launch_bounds__(256) void qkv_gemm(
    const __bf16* __restrict__ xb, const __bf16* __restrict__ wqb,
    const __bf16* __restrict__ wkb, const __bf16* __restrict__ wvb,
    const float* __restrict__ sint, const float* __restrict__ cost,
    __bf16* __restrict__ Qo, __bf16* __restrict__ Ko, __bf16* __restrict__ Vo)
{
    __shared__ __bf16 As[8192];   // [128 rows][64 cols], 128B rows, chunk-swizzled
    __shared__ __bf16 Bs[8192];
    const int tid = threadIdx.x;
    const int lane = tid & 63;
    const int wid = tid >> 6;
    const int wm = (wid >> 1) * 64, wn = (wid & 1) * 64;
    const int m0 = blockIdx.y * 128;
    const int n0 = blockIdx.x * 128;

    const __bf16* bsrc;
    if (n0 < 1024)      bsrc = wqb + (size_t)n0 * 1024;
    else if (n0 < 1536) bsrc = wkb + (size_t)(n0 - 1024) * 1024;
    else                bsrc = wvb + (size_t)(n0 - 1536) * 1024;
    const __bf16* asrc = xb + (size_t)m0 * 1024;

    f32x4 acc[4][4] = {};
    const int srow = tid >> 3, schunk = tid & 7;

    for (int k0 = 0; k0 < 1024; k0 += 64) {
        __syncthreads();
#pragma unroll
        for (int it = 0; it < 4; ++it) {
            int r = srow + it * 32;
            int gc = (schunk ^ (r & 7)) * 8;      // pre-swizzled global source chunk
            gload_lds16(asrc + (size_t)r * 1024 + k0 + gc, (char*)As + r * 128 + schunk * 16);
            gload_lds16(bsrc + (size_t)r * 1024 + k0 + gc, (char*)Bs + r * 128 + schunk * 16);
        }
        __syncthreads();
#pragma unroll
        for (int ks = 0; ks < 2; ++ks) {
            bf16x8 af[4], bfv[4];
#pragma unroll
            for (int i = 0; i < 4; ++i) {
                int ra = wm + i * 16 + (lane & 15);
                af[i] = *(const bf16x8*)((const char*)As + ra * 128 + (((ks * 4 + (lane >> 4)) ^ (ra & 7)) * 16));
                int rb = wn + i * 16 + (lane & 15);
                bfv[i] = *(const bf16x8*)((const char*)Bs + rb * 128 + (((ks * 4 + (lane >> 4)) ^ (rb & 7)) * 16));
            }
#pragma unroll
            for (int mi = 0; mi < 4; ++mi)
#pragma unroll
                for (int ni = 0; ni < 4; ++ni)
                    acc[mi][ni] = __builtin_amdgcn_mfma_f32_16x16x32_bf16(af[mi], bfv[ni], acc[mi][ni], 0, 0, 0);
        }
    }

    const int rg = lane >> 4, cf = lane & 15;
#pragma unroll
    for (int mi = 0; mi < 4; ++mi) {
#pragma unroll
        for (int ni = 0; ni < 4; ++ni) {
#pragma unroll
            for (int r = 0; r < 4; ++r) {
                float v = acc[mi][ni][r];
                float pv = __shfl_xor(v, 1, 64);    // partner column d^1 (same rows)
                int m = m0 + wm + mi * 16 + rg * 4 + r;
                int n = n0 + wn + ni * 16 + cf;
                int b = m >> 11;
                int t = m & 2047;
                if (n < 1024) {
                    int h = n >> 6, d = n & 63;
                    float s = sint[t * 32 + (d >> 1)], c = cost[t * 32 + (d >> 1)];
                    float o = (d & 1) ? (pv * s + v * c) : (v * c - pv * s);
                    Qo[((size_t)(b * 16 + h) * 2048 + t) * 64 + d] = (__bf16)(o * 0.125f);
                } else if (n < 1536) {
                    int nn = n - 1024;
                    int h = nn >> 6, d = nn & 63;
                    float s = sint[t * 32 + (d >> 1)], c = cost[t * 32 + (d >> 1)];
                    float o = (d & 1) ? (pv * s + v * c) : (v * c - pv * s);
                    Ko[((size_t)(b * 8 + h) * 2048 + t) * 64 + d] = (__bf16)o;
                } else {
                    int nn = n - 1536;
                    int h = nn >> 6, d = nn & 63;
                    Vo[((size_t)(b * 8 + h) * 2048 + t) * 64 + d] = (__bf16)v;
                }
            }
        }
    }
}

// ---------------- V transpose: V[bh][t][d] -> VT[bh][d][t] ----------------
__global__ __launch_bounds__(256) void v_transpose(const __bf16* __restrict__ Vg, __bf16* __restrict__ VTg)
{
    __shared__ __bf16 tile[64][72];
    const int tid = threadIdx.x;
    const int t0 = blockIdx.x * 64;
    const int bh = blockIdx.y;
    const size_t base = (size_t)bh * 2048 * 64;
    const int rr = tid >> 3, c8 = (tid & 7) * 8;
#pragma unroll
    for (int it = 0; it < 2; ++it) {
        int tt = rr + it * 32;
        *(bf16x8*)(&tile[tt][c8]) = *(const bf16x8*)(Vg + base + (size_t)(t0 + tt) * 64 + c8);
    }
    __syncthreads();
#pragma unroll
    for (int it = 0; it < 2; ++it) {
        int d = rr + it * 32;
        bf16x8 o;
#pragma unroll
        for (int j = 0; j < 8; ++j) o[j] = tile[c8 + j][d];
        *(bf16x8*)(VTg + base + (size_t)d * 2048 + t0 + c8) = o;
    }
}

// ---------------- Flash attention pass 1: split-KV partials ----------------
// XCD-aware decode (R5 bug: round-robin spread all 32 bh over every XCD -> 16MB
// working set vs 4MB L2 -> 774MB HBM churn). Now: xcd = lin&7 owns bh in
// {xcd, xcd+8, xcd+16, xcd+24} -> 2MB K/V working set per XCD L2.
// lin = blockIdx.x: xcd = lin&7, g = (lin>>3)&3, rem = lin>>5 (0..127).
// bh = xcd + 8g; j = 63-(rem>>1) (32-row q-tile), s = rem&1 (KV half).
// ntk = j/2+1 64-KV tiles; unit handles tiles [s*ntk/2, (s+1)*ntk/2).
// Diagonal tile is ALWAYS nt==ntk-1; mask needs rowoff = (j&1)*32.
__global__ __launch_bounds__(64, 4) void attn_part(
    const __bf16* __restrict__ Qg, const __bf16* __restrict__ Kg,
    const __bf16* __restrict__ VTg,
    __bf16* __restrict__ Op0, __bf16* __restrict__ Op1, float* __restrict__ mlp)
{
    __shared__ char Pl[4096];     // 32 rows x 64 cols bf16, swizzled
    const int lane = threadIdx.x & 63;
    const int u = blockIdx.x;                  // partial-buffer index (combine inverts this)
    const int xcd = u & 7;
    const int g = (u >> 3) & 3;
    const int rem = u >> 5;                    // 0..127
    const int bhu = xcd + 8 * g;
    const int j = 63 - (rem >> 1);
    const int s = rem & 1;
    const int b = bhu >> 4, h = bhu & 15, kvh = h >> 1;
    const int ntk = (j >> 1) + 1;
    const int lo = (s * ntk) >> 1;
    const int hi = ((s + 1) * ntk) >> 1;
    const int maskt = ntk - 1;                 // diagonal tile
    const int rowoff = (j & 1) * 32;           // odd j = upper half of the 64-row block
    const int r0 = j * 32;
    const size_t qbase = (size_t)(b * 16 + h) * 2048 * 64;
    const size_t kbase = (size_t)(b * 8 + kvh) * 2048 * 64;
    const int rg = lane >> 4, cf = lane & 15;

    // Q fragments in registers (already scaled by 0.125)
    bf16x8 qf[2][2];
#pragma unroll
    for (int mi = 0; mi < 2; ++mi)
#pragma unroll
        for (int ks = 0; ks < 2; ++ks)
            qf[mi][ks] = *(const bf16x8*)(Qg + qbase + (size_t)(r0 + mi * 16 + cf) * 64 + ks * 32 + rg * 8);

    f32x4 oacc[2][4] = {};
    float mst[2][4], lst[2][4];
#pragma unroll
    for (int i = 0; i < 2; ++i)
#pragma unroll
        for (int r = 0; r < 4; ++r) { mst[i][r] = -3.0e38f; lst[i][r] = 0.0f; }

    for (int nt = lo; nt < hi; ++nt) {
        const int n0 = nt * 64;
        // K fragments direct from global (L2-resident)
        bf16x8 kf[2][4];
#pragma unroll
        for (int ks = 0; ks < 2; ++ks)
#pragma unroll
            for (int ni = 0; ni < 4; ++ni)
                kf[ks][ni] = *(const bf16x8*)(Kg + kbase + (size_t)(n0 + ni * 16 + cf) * 64 + ks * 32 + rg * 8);

        // S = Q K^T
        f32x4 sacc[2][4] = {};
        __builtin_amdgcn_s_setprio(1);
#pragma unroll
        for (int ks = 0; ks < 2; ++ks)
#pragma unroll
            for (int mi = 0; mi < 2; ++mi)
#pragma unroll
                for (int ni = 0; ni < 4; ++ni)
                    sacc[mi][ni] = __builtin_amdgcn_mfma_f32_16x16x32_bf16(qf[mi][ks], kf[ks][ni], sacc[mi][ni], 0, 0, 0);
        __builtin_amdgcn_s_setprio(0);

        // V fragments for this tile (issued early, consumed after softmax)
        bf16x8 vf[2][4];
#pragma unroll
        for (int ks = 0; ks < 2; ++ks)
#pragma unroll
            for (int df = 0; df < 4; ++df)
                vf[ks][df] = *(const bf16x8*)(VTg + kbase + (size_t)(df * 16 + cf) * 2048 + n0 + ks * 32 + rg * 8);

        // causal mask on the diagonal tile
        if (nt == maskt) {
#pragma unroll
            for (int mi = 0; mi < 2; ++mi)
#pragma unroll
                for (int ni = 0; ni < 4; ++ni)
#pragma unroll
                    for (int r = 0; r < 4; ++r)
                        if (ni * 16 + cf > rowoff + mi * 16 + rg * 4 + r)
                            sacc[mi][ni][r] = -3.0e38f;
        }

        // online softmax (rows independent -> ILP)
#pragma unroll
        for (int mi = 0; mi < 2; ++mi) {
#pragma unroll
            for (int r = 0; r < 4; ++r) {
                float rmax = fmaxf(fmaxf(sacc[mi][0][r], sacc[mi][1][r]),
                                   fmaxf(sacc[mi][2][r], sacc[mi][3][r]));
#pragma unroll
                for (int off = 1; off < 16; off <<= 1)
                    rmax = fmaxf(rmax, __shfl_xor(rmax, off, 64));
                float mold = mst[mi][r];
                float mnew = fmaxf(mold, rmax);
                float sf = __expf(mold - mnew);
                float rs = 0.0f;
#pragma unroll
                for (int ni = 0; ni < 4; ++ni) {
                    float p = __expf(sacc[mi][ni][r] - mnew);
                    sacc[mi][ni][r] = p;
                    rs += p;
                }
#pragma unroll
                for (int off = 1; off < 16; off <<= 1)
                    rs += __shfl_xor(rs, off, 64);
                mst[mi][r] = mnew;
                lst[mi][r] = lst[mi][r] * sf + rs;
#pragma unroll
                for (int df = 0; df < 4; ++df) oacc[mi][df][r] *= sf;   // per-ROW rescale
            }
        }

        // P -> wave-local LDS (bf16, swizzled)
#pragma unroll
        for (int mi = 0; mi < 2; ++mi)
#pragma unroll
            for (int ni = 0; ni < 4; ++ni)
#pragma unroll
                for (int r = 0; r < 4; ++r) {
                    int pr = mi * 16 + rg * 4 + r;
                    int pc = ni * 16 + cf;
                    *(__bf16*)(Pl + pr * 128 + (((pc >> 3) ^ (pr & 7)) * 8 + (pc & 7)) * 2) =
                        (__bf16)sacc[mi][ni][r];
                }

        // O += P V
        __builtin_amdgcn_s_setprio(1);
#pragma unroll
        for (int ks = 0; ks < 2; ++ks) {
            bf16x8 pf[2];
#pragma unroll
            for (int mi = 0; mi < 2; ++mi) {
                int pr = mi * 16 + cf;
                pf[mi] = *(const bf16x8*)(Pl + pr * 128 + (((ks * 4 + rg) ^ (pr & 7)) * 16));
            }
#pragma unroll
            for (int mi = 0; mi < 2; ++mi)
#pragma unroll
                for (int df = 0; df < 4; ++df)
                    oacc[mi][df] = __builtin_amdgcn_mfma_f32_16x16x32_bf16(pf[mi], vf[ks][df], oacc[mi][df], 0, 0, 0);
        }
        __builtin_amdgcn_s_setprio(0);
    }

    // write partials (unnormalized O, m, l)
    __bf16* Op = (u < 3072) ? (Op0 + (size_t)u * 2048) : (Op1 + (size_t)(u - 3072) * 2048);
#pragma unroll
    for (int mi = 0; mi < 2; ++mi)
#pragma unroll
        for (int df = 0; df < 4; ++df)
#pragma unroll
            for (int r = 0; r < 4; ++r)
                Op[(mi * 16 + rg * 4 + r) * 64 + df * 16 + cf] = (__bf16)oacc[mi][df][r];
    if (cf == 0) {
#pragma unroll
        for (int mi = 0; mi < 2; ++mi)
#pragma unroll
            for (int r = 0; r < 4; ++r) {
                int row = mi * 16 + rg * 4 + r;
                mlp[u * 64 + row * 2]     = mst[mi][r];
                mlp[u * 64 + row * 2 + 1] = lst[mi][r];
            }
    }
}

// ---------------- Flash attention pass 2: combine the 2 splits ----------------
__global__ __launch_bounds__(64) void attn_combine(
    const __bf16* __restrict__ Op0, const __bf16* __restrict__ Op1,
    const float* __restrict__ mlp, __bf16* __restrict__ Yg)
{
    const int c = blockIdx.x;          // 0..2047
    const int bh = c >> 6, j = c & 63;
    const int b = bh >> 4, h = bh & 15;
    const int lane = threadIdx.x & 63;
    const int row = lane & 31, d0 = (lane >> 5) * 32;
    // invert attn_part's decode: u = rem*32 + g*8 + xcd, rem = (63-j)*2 + s
    const int u0 = (63 - j) * 64 + (bh >> 3) * 8 + (bh & 7);
    const int u1 = u0 + 32;
    const __bf16* P0 = ((u0 < 3072) ? (Op0 + (size_t)u0 * 2048) : (Op1 + (size_t)(u0 - 3072) * 2048)) + row * 64 + d0;
    const __bf16* P1 = ((u1 < 3072) ? (Op0 + (size_t)u1 * 2048) : (Op1 + (size_t)(u1 - 3072) * 2048)) + row * 64 + d0;
    float m0 = mlp[u0 * 64 + row * 2], l0 = mlp[u0 * 64 + row * 2 + 1];
    float m1 = mlp[u1 * 64 + row * 2], l1 = mlp[u1 * 64 + row * 2 + 1];
    float M = fmaxf(m0, m1);
    float w0 = __expf(m0 - M), w1 = __expf(m1 - M);
    float inv = 1.0f / (l0 * w0 + l1 * w1);
    int t = j * 32 + row;
    __bf16* yp = Yg + ((size_t)b * 2048 + t) * 1024 + h * 64 + d0;
#pragma unroll
    for (int cb = 0; cb < 4; ++cb) {
        bf16x8 a = *(const bf16x8*)(P0 + cb * 8);
        bf16x8 v = *(const bf16x8*)(P1 + cb * 8);
        bf16x8 o;
#pragma unroll
        for (int e = 0; e < 8; ++e)
            o[e] = (__bf16)(((float)a[e] * w0 + (float)v[e] * w1) * inv);
        *(bf16x8*)(yp + cb * 8) = o;
    }
}

// ---------------- Output projection GEMM: out = Y @ Wo^T (f32 out) ----------------
__global__ __launch_bounds__(256) void out_gemm(
    const __bf16* __restrict__ Yb, const __bf16* __restrict__ Wob, float* __restrict__ outp)
{
    __shared__ __bf16 As[8192];
    __shared__ __bf16 Bs[8192];
    const int tid = threadIdx.x;
    const int lane = tid & 63;
    const int wid = tid >> 6;
    const int wm = (wid >> 1) * 64, wn = (wid & 1) * 64;
    const int m0 = blockIdx.y * 128;
    const int n0 = blockIdx.x * 128;
    const __bf16* asrc = Yb + (size_t)m0 * 1024;
    const __bf16* bsrc = Wob + (size_t)n0 * 1024;

    f32x4 acc[4][4] = {};
    const int srow = tid >> 3, schunk = tid & 7;

    for (int k0 = 0; k0 < 1024; k0 += 64) {
        __syncthreads();
#pragma unroll
        for (int it = 0; it < 4; ++it) {
            int r = srow + it * 32;
            int gc = (schunk ^ (r & 7)) * 8;
            gload_lds16(asrc + (size_t)r * 1024 + k0 + gc, (char*)As + r * 128 + schunk * 16);
            gload_lds16(bsrc + (size_t)r * 1024 + k0 + gc, (char*)Bs + r * 128 + schunk * 16);
        }
        __syncthreads();
#pragma unroll
        for (int ks = 0; ks < 2; ++ks) {
            bf16x8 af[4], bfv[4];
#pragma unroll
            for (int i = 0; i < 4; ++i) {
                int ra = wm + i * 16 + (lane & 15);
                af[i] = *(const bf16x8*)((const char*)As + ra * 128 + (((ks * 4 + (lane >> 4)) ^ (ra & 7)) * 16));
                int rb = wn + i * 16 + (lane & 15);
                bfv[i] = *(const bf16x8*)((const char*)Bs + rb * 128 + (((ks * 4 + (lane >> 4)) ^ (rb & 7)) * 16));
            }
#pragma unroll
            for (int mi = 0; mi < 4; ++mi)
#pragma unroll
                for (int ni = 0; ni < 4; ++ni)
                    acc[mi][ni] = __builtin_amdgcn_mfma_f32_16x16x32_bf16(af[mi], bfv[ni], acc[mi][ni], 0, 0, 0);
        }
    }

    const int rg = lane >> 4, cf = lane & 15;
#pragma unroll
    for (int mi = 0; mi < 4; ++mi)
#pragma unroll
        for (int ni = 0; ni < 4; ++ni)
#pragma unroll
            for (int r = 0; r < 4; ++r) {
                int m = m0 + wm + mi * 16 + rg * 4 + r;
                int n = n0 + wn + ni * 16 + cf;
                outp[(size_t)m * 1024 + n] = acc[mi][ni][r];
            }
}

// ---------------- launch ----------------
extern "C" void kernel_launch(void* const* d_in, const int* in_sizes, int n_in,
                              void* d_out, int out_size, void* d_ws, size_t ws_size,
                              hipStream_t stream)
{
    const float* x  = (const float*)d_in[0];
    const float* wq = (const float*)d_in[1];
    const float* wk = (const float*)d_in[2];
    const float* wv = (const float*)d_in[3];
    const float* wo = (const float*)d_in[4];

    char* ws = (char*)d_ws;
    __bf16* xb  = (__bf16*)(ws + 0);          // 8,388,608 B
    __bf16* wqb = (__bf16*)(ws + 8388608);    // 2,097,152
    __bf16* wkb = (__bf16*)(ws + 10485760);   // 1,048,576
    __bf16* wvb = (__bf16*)(ws + 11534336);   // 1,048,576
    __bf16* wob = (__bf16*)(ws + 12582912);   // 2,097,152
    __bf16* Qb  = (__bf16*)(ws + 14680064);   // 8,388,608
    __bf16* Kb  = (__bf16*)(ws + 23068672);   // 4,194,304
    __bf16* Vb  = (__bf16*)(ws + 27262976);   // 4,194,304
    __bf16* VTb = (__bf16*)(ws + 31457280);   // 4,194,304
    __bf16* Yb  = (__bf16*)(ws + 35651584);   // 8,388,608
    float* sint = (float*)(ws + 44040192);    // 262,144
    float* cost = (float*)(ws + 44302336);    // 262,144
    // attn split-KV partials: Op0 overlays xb..wvb (dead after qkv_gemm), 3072 units
    __bf16* Op0 = (__bf16*)(ws + 0);          // 3072 * 4096 B = 12,582,912 (== xb+wqb+wkb+wvb)
    __bf16* Op1 = (__bf16*)(ws + 44564480);   // 1024 * 4096 B = 4,194,304
    float*  mlp = (float*)(ws + 48758784);    // 4096 * 256 B  = 1,048,576
    if (ws_size < 49807360) return;           // would fail loudly via absmax

    cvt_all<<<2048, 256, 0, stream>>>(x, wq, wk, wv, wo,
                                      (bf16x4*)xb, (bf16x4*)wqb, (bf16x4*)wkb,
                                      (bf16x4*)wvb, (bf16x4*)wob);
    rope_tables<<<256, 256, 0, stream>>>(sint, cost);
    qkv_gemm<<<dim3(16, 32), 256, 0, stream>>>(xb, wqb, wkb, wvb, sint, cost, Qb, Kb, Vb);
    v_transpose<<<dim3(32, 16), 256, 0, stream>>>(Vb, VTb);
    attn_part<<<4096, 64, 0, stream>>>(Qb, Kb, VTb, Op0, Op1, mlp);
    attn_combine<<<2048, 64, 0, stream>>>(Op0, Op1, mlp, Yb);
    out_gemm<<<dim3(8, 32), 256, 0, stream>>>(Yb, wob, (float*)d_out);
}

// Round 7
// 177.298 us; speedup vs baseline: 2.3427x; 2.0156x over previous
//
#include <hip/hip_runtime.h>
#include <cstdint>
#include <cstddef>

typedef __attribute__((ext_vector_type(8))) __bf16 bf16x8;
typedef __attribute__((ext_vector_type(4))) __bf16 bf16x4;
typedef __attribute__((ext_vector_type(4))) float f32x4;

#define DEVI __device__ __forceinline__

DEVI void gload_lds16(const void* g, void* l) {
    __builtin_amdgcn_global_load_lds((const __attribute__((address_space(1))) void*)g,
                                     (__attribute__((address_space(3))) void*)l, 16, 0, 0);
}

// ---------------- f32 -> bf16 conversion of x and all weights ----------------
__global__ __launch_bounds__(256) void cvt_all(
    const float* __restrict__ x, const float* __restrict__ wq,
    const float* __restrict__ wk, const float* __restrict__ wv,
    const float* __restrict__ wo,
    bf16x4* __restrict__ xb, bf16x4* __restrict__ wqb, bf16x4* __restrict__ wkb,
    bf16x4* __restrict__ wvb, bf16x4* __restrict__ wob)
{
    int i = blockIdx.x * 256 + threadIdx.x;
    const int stride = gridDim.x * 256;
    for (; i < 1835008; i += stride) {
        const float4* s; bf16x4* d; int j;
        if (i < 1048576)      { s = (const float4*)x;  d = xb;  j = i; }
        else if (i < 1310720) { s = (const float4*)wq; d = wqb; j = i - 1048576; }
        else if (i < 1441792) { s = (const float4*)wk; d = wkb; j = i - 1310720; }
        else if (i < 1572864) { s = (const float4*)wv; d = wvb; j = i - 1441792; }
        else                  { s = (const float4*)wo; d = wob; j = i - 1572864; }
        float4 v = s[j];
        bf16x4 o = { (__bf16)v.x, (__bf16)v.y, (__bf16)v.z, (__bf16)v.w };
        d[j] = o;
    }
}

// ---------------- RoPE tables: sin/cos[t][pair], T=2048, 32 pairs ----------------
__global__ __launch_bounds__(256) void rope_tables(float* __restrict__ sint, float* __restrict__ cost)
{
    int i = blockIdx.x * 256 + threadIdx.x;   // 0..65535
    int t = i >> 5, p = i & 31;
    float inv = powf(10000.0f, -(float)p / 32.0f);
    float f = (float)t * inv;
    float s, c;
    sincosf(f, &s, &c);
    sint[i] = s;
    cost[i] = c;
}

// ---------------- QKV projection GEMM (128x128 tile, BK=64, bf16 MFMA) ----------------
__global__ __launch_bounds__(256) void qkv_gemm(
    const __bf16* __restrict__ xb, const __bf16* __restrict__ wqb,
    const __bf16* __restrict__ wkb, const __bf16* __restrict__ wvb,
    const float* __restrict__ sint, const float* __restrict__ cost,
    __bf16* __restrict__ Qo, __bf16* __restrict__ Ko, __bf16* __restrict__ Vo)
{
    __shared__ __bf16 As[8192];   // [128 rows][64 cols], 128B rows, chunk-swizzled
    __shared__ __bf16 Bs[8192];
    const int tid = threadIdx.x;
    const int lane = tid & 63;
    const int wid = tid >> 6;
    const int wm = (wid >> 1) * 64, wn = (wid & 1) * 64;
    const int m0 = blockIdx.y * 128;
    const int n0 = blockIdx.x * 128;

    const __bf16* bsrc;
    if (n0 < 1024)      bsrc = wqb + (size_t)n0 * 1024;
    else if (n0 < 1536) bsrc = wkb + (size_t)(n0 - 1024) * 1024;
    else                bsrc = wvb + (size_t)(n0 - 1536) * 1024;
    const __bf16* asrc = xb + (size_t)m0 * 1024;

    f32x4 acc[4][4] = {};
    const int srow = tid >> 3, schunk = tid & 7;

    for (int k0 = 0; k0 < 1024; k0 += 64) {
        __syncthreads();
#pragma unroll
        for (int it = 0; it < 4; ++it) {
            int r = srow + it * 32;
            int gc = (schunk ^ (r & 7)) * 8;      // pre-swizzled global source chunk
            gload_lds16(asrc + (size_t)r * 1024 + k0 + gc, (char*)As + r * 128 + schunk * 16);
            gload_lds16(bsrc + (size_t)r * 1024 + k0 + gc, (char*)Bs + r * 128 + schunk * 16);
        }
        __syncthreads();
#pragma unroll
        for (int ks = 0; ks < 2; ++ks) {
            bf16x8 af[4], bfv[4];
#pragma unroll
            for (int i = 0; i < 4; ++i) {
                int ra = wm + i * 16 + (lane & 15);
                af[i] = *(const bf16x8*)((const char*)As + ra * 128 + (((ks * 4 + (lane >> 4)) ^ (ra & 7)) * 16));
                int rb = wn + i * 16 + (lane & 15);
                bfv[i] = *(const bf16x8*)((const char*)Bs + rb * 128 + (((ks * 4 + (lane >> 4)) ^ (rb & 7)) * 16));
            }
#pragma unroll
            for (int mi = 0; mi < 4; ++mi)
#pragma unroll
                for (int ni = 0; ni < 4; ++ni)
                    acc[mi][ni] = __builtin_amdgcn_mfma_f32_16x16x32_bf16(af[mi], bfv[ni], acc[mi][ni], 0, 0, 0);
        }
    }

    const int rg = lane >> 4, cf = lane & 15;
#pragma unroll
    for (int mi = 0; mi < 4; ++mi) {
#pragma unroll
        for (int ni = 0; ni < 4; ++ni) {
#pragma unroll
            for (int r = 0; r < 4; ++r) {
                float v = acc[mi][ni][r];
                float pv = __shfl_xor(v, 1, 64);    // partner column d^1 (same rows)
                int m = m0 + wm + mi * 16 + rg * 4 + r;
                int n = n0 + wn + ni * 16 + cf;
                int b = m >> 11;
                int t = m & 2047;
                if (n < 1024) {
                    int h = n >> 6, d = n & 63;
                    float s = sint[t * 32 + (d >> 1)], c = cost[t * 32 + (d >> 1)];
                    float o = (d & 1) ? (pv * s + v * c) : (v * c - pv * s);
                    Qo[((size_t)(b * 16 + h) * 2048 + t) * 64 + d] = (__bf16)(o * 0.125f);
                } else if (n < 1536) {
                    int nn = n - 1024;
                    int h = nn >> 6, d = nn & 63;
                    float s = sint[t * 32 + (d >> 1)], c = cost[t * 32 + (d >> 1)];
                    float o = (d & 1) ? (pv * s + v * c) : (v * c - pv * s);
                    Ko[((size_t)(b * 8 + h) * 2048 + t) * 64 + d] = (__bf16)o;
                } else {
                    int nn = n - 1536;
                    int h = nn >> 6, d = nn & 63;
                    Vo[((size_t)(b * 8 + h) * 2048 + t) * 64 + d] = (__bf16)v;
                }
            }
        }
    }
}

// ---------------- V transpose: V[bh][t][d] -> VT[bh][d][t] ----------------
__global__ __launch_bounds__(256) void v_transpose(const __bf16* __restrict__ Vg, __bf16* __restrict__ VTg)
{
    __shared__ __bf16 tile[64][72];
    const int tid = threadIdx.x;
    const int t0 = blockIdx.x * 64;
    const int bh = blockIdx.y;
    const size_t base = (size_t)bh * 2048 * 64;
    const int rr = tid >> 3, c8 = (tid & 7) * 8;
#pragma unroll
    for (int it = 0; it < 2; ++it) {
        int tt = rr + it * 32;
        *(bf16x8*)(&tile[tt][c8]) = *(const bf16x8*)(Vg + base + (size_t)(t0 + tt) * 64 + c8);
    }
    __syncthreads();
#pragma unroll
    for (int it = 0; it < 2; ++it) {
        int d = rr + it * 32;
        bf16x8 o;
#pragma unroll
        for (int j = 0; j < 8; ++j) o[j] = tile[c8 + j][d];
        *(bf16x8*)(VTg + base + (size_t)d * 2048 + t0 + c8) = o;
    }
}

// ---------------- Flash attention, monolithic + uniform q-tile pairing ----------------
// Block (bh, p): processes 64-row q-tile j=p (p+1 kv tiles) then j=31-p (32-p tiles)
// -> 33 tiles for EVERY block (zero tail skew). 2 independent waves split rows by w*32.
// All blocks start nt=0 together -> phase-coherent L2 reuse (the property that gave R3
// its 12MB FETCH; split-KV's staggered phases thrashed L2 at 360+MB).
// K fragments for tile nt+1 prefetched into registers during tile nt's softmax/PV.
__global__ __launch_bounds__(128) void attn_fwd(
    const __bf16* __restrict__ Qg, const __bf16* __restrict__ Kg,
    const __bf16* __restrict__ VTg, __bf16* __restrict__ Yg)
{
    __shared__ char Pl[8192];     // 2 waves x 4KB (32 rows x 64 cols bf16, swizzled)
    const int tid = threadIdx.x;
    const int lane = tid & 63;
    const int w = tid >> 6;
    const int lin = blockIdx.x;               // 512 blocks
    const int xcd = lin & 7, g = (lin >> 3) & 3, p = lin >> 5;   // p in 0..15
    const int bh = xcd + 8 * g;               // XCD owns 4 bh
    const int b = bh >> 4, h = bh & 15, kvh = h >> 1;
    const size_t qbase = (size_t)(b * 16 + h) * 2048 * 64;
    const size_t kbase = (size_t)(b * 8 + kvh) * 2048 * 64;
    const int rg = lane >> 4, cf = lane & 15;
    char* pw = Pl + w * 4096;

#define LOADK(KF, NT) do {                                                              \
    const int _n0 = (NT) * 64;                                                          \
    _Pragma("unroll") for (int ks = 0; ks < 2; ++ks)                                    \
    _Pragma("unroll") for (int ni = 0; ni < 4; ++ni)                                    \
        KF[ks][ni] = *(const bf16x8*)(Kg + kbase + (size_t)(_n0 + ni * 16 + cf) * 64 + ks * 32 + rg * 8); \
} while (0)

#define TILE(KF, NT) do {                                                               \
    const int _n0 = (NT) * 64;                                                          \
    f32x4 sacc[2][4] = {};                                                              \
    __builtin_amdgcn_s_setprio(1);                                                      \
    _Pragma("unroll") for (int ks = 0; ks < 2; ++ks)                                    \
    _Pragma("unroll") for (int mi = 0; mi < 2; ++mi)                                    \
    _Pragma("unroll") for (int ni = 0; ni < 4; ++ni)                                    \
        sacc[mi][ni] = __builtin_amdgcn_mfma_f32_16x16x32_bf16(qf[mi][ks], KF[ks][ni], sacc[mi][ni], 0, 0, 0); \
    __builtin_amdgcn_s_setprio(0);                                                      \
    bf16x8 vf[2][4];                                                                    \
    _Pragma("unroll") for (int ks = 0; ks < 2; ++ks)                                    \
    _Pragma("unroll") for (int df = 0; df < 4; ++df)                                    \
        vf[ks][df] = *(const bf16x8*)(VTg + kbase + (size_t)(df * 16 + cf) * 2048 + _n0 + ks * 32 + rg * 8); \
    if ((NT) == j) {                                                                    \
        _Pragma("unroll") for (int mi = 0; mi < 2; ++mi)                                \
        _Pragma("unroll") for (int ni = 0; ni < 4; ++ni)                                \
        _Pragma("unroll") for (int r = 0; r < 4; ++r)                                   \
            if (ni * 16 + cf > w * 32 + mi * 16 + rg * 4 + r)                           \
                sacc[mi][ni][r] = -3.0e38f;                                             \
    }                                                                                   \
    _Pragma("unroll") for (int mi = 0; mi < 2; ++mi) {                                  \
    _Pragma("unroll") for (int r = 0; r < 4; ++r) {                                     \
        float rmax = fmaxf(fmaxf(sacc[mi][0][r], sacc[mi][1][r]),                       \
                           fmaxf(sacc[mi][2][r], sacc[mi][3][r]));                      \
        _Pragma("unroll") for (int off = 1; off < 16; off <<= 1)                        \
            rmax = fmaxf(rmax, __shfl_xor(rmax, off, 64));                              \
        float mold = mst[mi][r];                                                        \
        float mnew = fmaxf(mold, rmax);                                                 \
        float sf = __expf(mold - mnew);                                                 \
        float rs = 0.0f;                                                                \
        _Pragma("unroll") for (int ni = 0; ni < 4; ++ni) {                              \
            float pe = __expf(sacc[mi][ni][r] - mnew);                                  \
            sacc[mi][ni][r] = pe;                                                       \
            rs += pe;                                                                   \
        }                                                                               \
        _Pragma("unroll") for (int off = 1; off < 16; off <<= 1)                        \
            rs += __shfl_xor(rs, off, 64);                                              \
        mst[mi][r] = mnew;                                                              \
        lst[mi][r] = lst[mi][r] * sf + rs;                                              \
        _Pragma("unroll") for (int df = 0; df < 4; ++df) oacc[mi][df][r] *= sf;         \
    } }                                                                                 \
    _Pragma("unroll") for (int mi = 0; mi < 2; ++mi)                                    \
    _Pragma("unroll") for (int ni = 0; ni < 4; ++ni)                                    \
    _Pragma("unroll") for (int r = 0; r < 4; ++r) {                                     \
        int pr = mi * 16 + rg * 4 + r;                                                  \
        int pc = ni * 16 + cf;                                                          \
        *(__bf16*)(pw + pr * 128 + (((pc >> 3) ^ (pr & 7)) * 8 + (pc & 7)) * 2) =       \
            (__bf16)sacc[mi][ni][r];                                                    \
    }                                                                                   \
    __builtin_amdgcn_s_setprio(1);                                                      \
    _Pragma("unroll") for (int ks = 0; ks < 2; ++ks) {                                  \
        bf16x8 pf[2];                                                                   \
        _Pragma("unroll") for (int mi = 0; mi < 2; ++mi) {                              \
            int pr = mi * 16 + cf;                                                      \
            pf[mi] = *(const bf16x8*)(pw + pr * 128 + (((ks * 4 + rg) ^ (pr & 7)) * 16)); \
        }                                                                               \
        _Pragma("unroll") for (int mi = 0; mi < 2; ++mi)                                \
        _Pragma("unroll") for (int df = 0; df < 4; ++df)                                \
            oacc[mi][df] = __builtin_amdgcn_mfma_f32_16x16x32_bf16(pf[mi], vf[ks][df], oacc[mi][df], 0, 0, 0); \
    }                                                                                   \
    __builtin_amdgcn_s_setprio(0);                                                      \
} while (0)

#pragma unroll 1
    for (int ji = 0; ji < 2; ++ji) {
        const int j = ji ? (31 - p) : p;      // 64-row q-tile index, kv tiles 0..j
        const int ntiles = j + 1;
        const int r0 = j * 64 + w * 32;       // this wave's first Q row

        bf16x8 qf[2][2];
#pragma unroll
        for (int mi = 0; mi < 2; ++mi)
#pragma unroll
            for (int ks = 0; ks < 2; ++ks)
                qf[mi][ks] = *(const bf16x8*)(Qg + qbase + (size_t)(r0 + mi * 16 + cf) * 64 + ks * 32 + rg * 8);

        f32x4 oacc[2][4] = {};
        float mst[2][4], lst[2][4];
#pragma unroll
        for (int i = 0; i < 2; ++i)
#pragma unroll
            for (int r = 0; r < 4; ++r) { mst[i][r] = -3.0e38f; lst[i][r] = 0.0f; }

        bf16x8 kfA[2][4], kfB[2][4];
        LOADK(kfA, 0);
        int nt = 0;
        while (true) {
            if (nt + 1 < ntiles) LOADK(kfB, nt + 1);     // prefetch next K under this tile
            TILE(kfA, nt);
            ++nt; if (nt >= ntiles) break;
            if (nt + 1 < ntiles) LOADK(kfA, nt + 1);
            TILE(kfB, nt);
            ++nt; if (nt >= ntiles) break;
        }

        // epilogue: Y[b][t][h*64+d] = O / l   (bf16)
#pragma unroll
        for (int mi = 0; mi < 2; ++mi)
#pragma unroll
            for (int r = 0; r < 4; ++r) {
                float inv = 1.0f / lst[mi][r];
                int t = r0 + mi * 16 + rg * 4 + r;
#pragma unroll
                for (int df = 0; df < 4; ++df)
                    Yg[((size_t)b * 2048 + t) * 1024 + h * 64 + df * 16 + cf] =
                        (__bf16)(oacc[mi][df][r] * inv);
            }
    }
#undef LOADK
#undef TILE
}

// ---------------- Output projection GEMM: out = Y @ Wo^T (f32 out) ----------------
__global__ __launch_bounds__(256) void out_gemm(
    const __bf16* __restrict__ Yb, const __bf16* __restrict__ Wob, float* __restrict__ outp)
{
    __shared__ __bf16 As[8192];
    __shared__ __bf16 Bs[8192];
    const int tid = threadIdx.x;
    const int lane = tid & 63;
    const int wid = tid >> 6;
    const int wm = (wid >> 1) * 64, wn = (wid & 1) * 64;
    const int m0 = blockIdx.y * 128;
    const int n0 = blockIdx.x * 128;
    const __bf16* asrc = Yb + (size_t)m0 * 1024;
    const __bf16* bsrc = Wob + (size_t)n0 * 1024;

    f32x4 acc[4][4] = {};
    const int srow = tid >> 3, schunk = tid & 7;

    for (int k0 = 0; k0 < 1024; k0 += 64) {
        __syncthreads();
#pragma unroll
        for (int it = 0; it < 4; ++it) {
            int r = srow + it * 32;
            int gc = (schunk ^ (r & 7)) * 8;
            gload_lds16(asrc + (size_t)r * 1024 + k0 + gc, (char*)As + r * 128 + schunk * 16);
            gload_lds16(bsrc + (size_t)r * 1024 + k0 + gc, (char*)Bs + r * 128 + schunk * 16);
        }
        __syncthreads();
#pragma unroll
        for (int ks = 0; ks < 2; ++ks) {
            bf16x8 af[4], bfv[4];
#pragma unroll
            for (int i = 0; i < 4; ++i) {
                int ra = wm + i * 16 + (lane & 15);
                af[i] = *(const bf16x8*)((const char*)As + ra * 128 + (((ks * 4 + (lane >> 4)) ^ (ra & 7)) * 16));
                int rb = wn + i * 16 + (lane & 15);
                bfv[i] = *(const bf16x8*)((const char*)Bs + rb * 128 + (((ks * 4 + (lane >> 4)) ^ (rb & 7)) * 16));
            }
#pragma unroll
            for (int mi = 0; mi < 4; ++mi)
#pragma unroll
                for (int ni = 0; ni < 4; ++ni)
                    acc[mi][ni] = __builtin_amdgcn_mfma_f32_16x16x32_bf16(af[mi], bfv[ni], acc[mi][ni], 0, 0, 0);
        }
    }

    const int rg = lane >> 4, cf = lane & 15;
#pragma unroll
    for (int mi = 0; mi < 4; ++mi)
#pragma unroll
        for (int ni = 0; ni < 4; ++ni)
#pragma unroll
            for (int r = 0; r < 4; ++r) {
                int m = m0 + wm + mi * 16 + rg * 4 + r;
                int n = n0 + wn + ni * 16 + cf;
                outp[(size_t)m * 1024 + n] = acc[mi][ni][r];
            }
}

// ---------------- launch ----------------
extern "C" void kernel_launch(void* const* d_in, const int* in_sizes, int n_in,
                              void* d_out, int out_size, void* d_ws, size_t ws_size,
                              hipStream_t stream)
{
    const float* x  = (const float*)d_in[0];
    const float* wq = (const float*)d_in[1];
    const float* wk = (const float*)d_in[2];
    const float* wv = (const float*)d_in[3];
    const float* wo = (const float*)d_in[4];

    char* ws = (char*)d_ws;
    __bf16* xb  = (__bf16*)(ws + 0);          // 8,388,608 B
    __bf16* wqb = (__bf16*)(ws + 8388608);    // 2,097,152
    __bf16* wkb = (__bf16*)(ws + 10485760);   // 1,048,576
    __bf16* wvb = (__bf16*)(ws + 11534336);   // 1,048,576
    __bf16* wob = (__bf16*)(ws + 12582912);   // 2,097,152
    __bf16* Qb  = (__bf16*)(ws + 14680064);   // 8,388,608
    __bf16* Kb  = (__bf16*)(ws + 23068672);   // 4,194,304
    __bf16* Vb  = (__bf16*)(ws + 27262976);   // 4,194,304
    __bf16* VTb = (__bf16*)(ws + 31457280);   // 4,194,304
    __bf16* Yb  = (__bf16*)(ws + 35651584);   // 8,388,608
    float* sint = (float*)(ws + 44040192);    // 262,144
    float* cost = (float*)(ws + 44302336);    // 262,144
    if (ws_size < 44564480) return;           // would fail loudly via absmax

    cvt_all<<<2048, 256, 0, stream>>>(x, wq, wk, wv, wo,
                                      (bf16x4*)xb, (bf16x4*)wqb, (bf16x4*)wkb,
                                      (bf16x4*)wvb, (bf16x4*)wob);
    rope_tables<<<256, 256, 0, stream>>>(sint, cost);
    qkv_gemm<<<dim3(16, 32), 256, 0, stream>>>(xb, wqb, wkb, wvb, sint, cost, Qb, Kb, Vb);
    v_transpose<<<dim3(32, 16), 256, 0, stream>>>(Vb, VTb);
    attn_fwd<<<512, 128, 0, stream>>>(Qb, Kb, VTb, Yb);
    out_gemm<<<dim3(8, 32), 256, 0, stream>>>(Yb, wob, (float*)d_out);
}